// Round 5
// baseline (493.328 us; speedup 1.0000x reference)
//
#include <hip/hip_runtime.h>
#include <cstdint>
#include <cstddef>

// ---- problem constants ----
#define B_    4
#define S_    2048
#define D_    1024
#define H_    16
#define HD_   64
#define M_    8192      // B_*S_
#define NQKV  3072

typedef __bf16 bf16;
typedef __bf16 bf16x4 __attribute__((ext_vector_type(4)));
typedef __bf16 bf16x8 __attribute__((ext_vector_type(8)));
typedef float  f32x2  __attribute__((ext_vector_type(2)));
typedef float  f32x4  __attribute__((ext_vector_type(4)));
typedef float  f32x16 __attribute__((ext_vector_type(16)));
typedef unsigned short u16x4 __attribute__((ext_vector_type(4)));
typedef uint32_t u32x2 __attribute__((ext_vector_type(2)));
typedef uint32_t u32x4 __attribute__((ext_vector_type(4)));

// async global->LDS, 16B per lane. LDS dest is wave-uniform base + lane*16.
__device__ __forceinline__ void gl2lds16(const void* g, void* l) {
  __builtin_amdgcn_global_load_lds(
      (__attribute__((address_space(1))) void*)(uintptr_t)g,
      (__attribute__((address_space(3))) void*)l, 16, 0, 0);
}

__device__ __forceinline__ uint32_t pkbf16(float a, float b) {
  union { bf16 h[2]; uint32_t u; } z;
  z.h[0] = (bf16)a; z.h[1] = (bf16)b;
  return z.u;
}

// ---- prep: fp32 -> bf16 cast (x) ----
__global__ __launch_bounds__(256) void cast_f32_bf16(const float* __restrict__ in,
                                                     bf16* __restrict__ out, int n4) {
  int i = blockIdx.x * 256 + threadIdx.x;
  if (i >= n4) return;
  float4 v = ((const float4*)in)[i];
  bf16x4 o;
  o[0] = (bf16)v.x; o[1] = (bf16)v.y; o[2] = (bf16)v.z; o[3] = (bf16)v.w;
  ((bf16x4*)out)[i] = o;
}

// ---- prep: transpose + cast: in [R,C] fp32 -> out [C,R] bf16 ----
__global__ __launch_bounds__(256) void transpose_cast(const float* __restrict__ in,
                                                      bf16* __restrict__ out, int R, int C) {
  __shared__ float tile[32][33];
  int bx = blockIdx.x * 32, by = blockIdx.y * 32;
  int tx = threadIdx.x, ty = threadIdx.y;
#pragma unroll
  for (int i = 0; i < 32; i += 8)
    tile[ty + i][tx] = in[(size_t)(by + ty + i) * C + bx + tx];
  __syncthreads();
#pragma unroll
  for (int i = 0; i < 32; i += 8)
    out[(size_t)(bx + ty + i) * R + by + tx] = (bf16)tile[tx][ty + i];
}

// ---- 128x128 GEMM w/ XCD super-tiling: C[M,N] = A[M,K]*Bt[N,K]^T + bias ----
template <bool OUT_BF16>
__global__ __launch_bounds__(256) void gemm_bt(const bf16* __restrict__ A,
                                               const bf16* __restrict__ Bt,
                                               const float* __restrict__ bias,
                                               void* __restrict__ Cptr,
                                               int M, int N, int K) {
  __shared__ __align__(16) bf16 As[128 * 64];
  __shared__ __align__(16) bf16 Bs[128 * 64];
  const int tid  = threadIdx.x;
  const int lane = tid & 63, w = tid >> 6;
  const int lo   = lane & 15, quad = lane >> 4;
  const int xcd = blockIdx.x & 7, g = blockIdx.x >> 3;
  const int mi  = g & 7,          n = g >> 3;
  const int bm  = (xcd * 8 + mi) * 128, bn = n * 128;
  const int wm = (w >> 1) * 64,    wn = (w & 1) * 64;

  f32x4 acc[4][4];
  const f32x4 zero = {0.f, 0.f, 0.f, 0.f};
#pragma unroll
  for (int i = 0; i < 4; ++i)
#pragma unroll
    for (int j = 0; j < 4; ++j) acc[i][j] = zero;

  for (int k0 = 0; k0 < K; k0 += 64) {
#pragma unroll
    for (int c = 0; c < 4; ++c) {
      int seg = c * 4 + w;
      int idx = seg * 512 + lane * 8;
      int row = idx >> 6, col = idx & 63;
      gl2lds16(A  + (size_t)(bm + row) * K + k0 + col, As + seg * 512);
      gl2lds16(Bt + (size_t)(bn + row) * K + k0 + col, Bs + seg * 512);
    }
    __syncthreads();
#pragma unroll
    for (int ks = 0; ks < 2; ++ks) {
      bf16x8 av[4], bv[4];
#pragma unroll
      for (int i = 0; i < 4; ++i)
        av[i] = *(const bf16x8*)&As[(wm + i * 16 + lo) * 64 + ks * 32 + quad * 8];
#pragma unroll
      for (int j = 0; j < 4; ++j)
        bv[j] = *(const bf16x8*)&Bs[(wn + j * 16 + lo) * 64 + ks * 32 + quad * 8];
#pragma unroll
      for (int i = 0; i < 4; ++i)
#pragma unroll
        for (int j = 0; j < 4; ++j)
          acc[i][j] = __builtin_amdgcn_mfma_f32_16x16x32_bf16(av[i], bv[j], acc[i][j], 0, 0, 0);
    }
    __syncthreads();
  }
#pragma unroll
  for (int j = 0; j < 4; ++j) {
    int cg = bn + wn + j * 16 + lo;
    float bsv = bias[cg];
#pragma unroll
    for (int i = 0; i < 4; ++i) {
      int rg = bm + wm + i * 16 + quad * 4;
#pragma unroll
      for (int r = 0; r < 4; ++r) {
        float v = acc[i][j][r] + bsv;
        if (OUT_BF16) ((bf16*)Cptr)[(size_t)(rg + r) * N + cg] = (bf16)v;
        else          ((float*)Cptr)[(size_t)(rg + r) * N + cg] = v;
      }
    }
  }
}

// ---- 128x256 GEMM (qkv) ----
__global__ __launch_bounds__(256, 2) void gemm_bt_wide(const bf16* __restrict__ A,
                                                       const bf16* __restrict__ Bt,
                                                       const float* __restrict__ bias,
                                                       bf16* __restrict__ Cptr,
                                                       int M, int N, int K) {
  __shared__ __align__(16) bf16 As[128 * 64];   // 16 KB
  __shared__ __align__(16) bf16 Bs[256 * 64];   // 32 KB
  const int tid  = threadIdx.x;
  const int lane = tid & 63, w = tid >> 6;
  const int lo   = lane & 15, quad = lane >> 4;
  const int xcd = blockIdx.x & 7, g = blockIdx.x >> 3;
  const int mi  = g & 7,          n = g >> 3;
  const int bm  = (xcd * 8 + mi) * 128, bn = n * 256;
  const int wm = (w >> 1) * 64,    wn = (w & 1) * 128;

  f32x4 acc[4][8];
  const f32x4 zero = {0.f, 0.f, 0.f, 0.f};
#pragma unroll
  for (int i = 0; i < 4; ++i)
#pragma unroll
    for (int j = 0; j < 8; ++j) acc[i][j] = zero;

  for (int k0 = 0; k0 < K; k0 += 64) {
#pragma unroll
    for (int c = 0; c < 4; ++c) {
      int seg = c * 4 + w;
      int idx = seg * 512 + lane * 8;
      int row = idx >> 6, col = idx & 63;
      gl2lds16(A + (size_t)(bm + row) * K + k0 + col, As + seg * 512);
    }
#pragma unroll
    for (int c = 0; c < 8; ++c) {
      int seg = c * 4 + w;
      int idx = seg * 512 + lane * 8;
      int row = idx >> 6, col = idx & 63;
      gl2lds16(Bt + (size_t)(bn + row) * K + k0 + col, Bs + seg * 512);
    }
    __syncthreads();
#pragma unroll
    for (int ks = 0; ks < 2; ++ks) {
      bf16x8 av[4], bv[8];
#pragma unroll
      for (int i = 0; i < 4; ++i)
        av[i] = *(const bf16x8*)&As[(wm + i * 16 + lo) * 64 + ks * 32 + quad * 8];
#pragma unroll
      for (int j = 0; j < 8; ++j)
        bv[j] = *(const bf16x8*)&Bs[(wn + j * 16 + lo) * 64 + ks * 32 + quad * 8];
#pragma unroll
      for (int i = 0; i < 4; ++i)
#pragma unroll
        for (int j = 0; j < 8; ++j)
          acc[i][j] = __builtin_amdgcn_mfma_f32_16x16x32_bf16(av[i], bv[j], acc[i][j], 0, 0, 0);
    }
    __syncthreads();
  }
#pragma unroll
  for (int j = 0; j < 8; ++j) {
    int cg = bn + wn + j * 16 + lo;
    float bsv = bias[cg];
#pragma unroll
    for (int i = 0; i < 4; ++i) {
      int rg = bm + wm + i * 16 + quad * 4;
#pragma unroll
      for (int r = 0; r < 4; ++r)
        Cptr[(size_t)(rg + r) * N + cg] = (bf16)(acc[i][j][r] + bsv);
    }
  }
}

// ---- flash attention v13: intra-block KV split, 8 waves ----
// R4 verdict: counted waits (v12) did NOT help -> not barrier-drain-bound but
// execution-latency-bound at 2 waves/SIMD (Occ 17.7, grid 512 = 2 blk/CU).
// v13: 512-thread blocks, two 4-wave groups; group g runs v11's exact loop
// over KV tiles g*16..g*16+15 with its own 32 KB K/V dbuf (64 KB LDS total ->
// 2 blk/CU, 16 waves/CU = 4 waves/SIMD, 2x v11). Fixed-exponent softmax makes
// partials additive: epilogue = lsum exchange (2 KB LDS) + group-0 O^T f32
// partial through per-wave 16 KB LDS slices (XOR chunk swizzle, read-before-
// write order per wave), group 1 adds in regs, normalizes, writes swizzled
// bf16 Os; all 8 waves coalesced-store. launch_bounds(512,4) -> 128-reg cap;
// budget ~110. Tripwire: WRITE_SIZE ~22 MB (spill check).
__global__ __launch_bounds__(512, 4) void flash_attn(const bf16* __restrict__ qkv,
                                                     bf16* __restrict__ out) {
  __shared__ __align__(16) bf16 smem[32768];   // 64 KB

  const int tid  = threadIdx.x;
  const int lane = tid & 63;
  const int wq   = (tid >> 6) & 3;      // wave within group
  const int grp  = tid >> 8;            // KV half
  const int t8   = tid & 255;           // thread within group
  const int l31  = lane & 31;
  const int e    = lane >> 5;
  const int hi8  = e * 8;

  const int bid = blockIdx.x;
  const int qb  = bid >> 6;             // 0..7 (256 q each)
  const int bh  = bid & 63;
  const int h   = bh & 15;
  const int b   = bh >> 4;
  const int q0  = qb * 256;
  const size_t rowb = (size_t)b * S_;
  const bf16* qbase = qkv + rowb * NQKV + h * HD_;
  const bf16* kbase = qbase + D_     + (size_t)(grp * 16) * 64 * NQKV;
  const bf16* vbase = qbase + 2 * D_ + (size_t)(grp * 16) * 64 * NQKV;

  bf16* const Ksg = smem + grp * 16384;   // [2][4096] per group
  bf16* const Vsg = Ksg + 8192;           // [2][4096]

  // ---- Q fragments for the wave's TWO q-subblocks (same q range both groups) ----
  bf16x8 qfA[4], qfB[4];
  {
    const bf16* qrow0 = qbase + (size_t)(q0 + wq * 64 + l31) * NQKV;
    const bf16* qrow1 = qrow0 + (size_t)32 * NQKV;
#pragma unroll
    for (int c = 0; c < 4; ++c) {
      qfA[c] = *(const bf16x8*)(qrow0 + c * 16 + hi8);
      qfB[c] = *(const bf16x8*)(qrow1 + c * 16 + hi8);
    }
  }

  // ---- K DMA indices (within group) ----
  int kq_off[2];
#pragma unroll
  for (int it = 0; it < 2; ++it) {
    int ci = it * 256 + t8;
    int s  = ci >> 3;
    int x  = (ci & 7) ^ (s & 7);
    kq_off[it] = s * NQKV + x * 8;
  }
  // ---- V staging indices (within group) ----
  int vs_d[2], vs_s[2], vs_off[2];
#pragma unroll
  for (int u = 0; u < 2; ++u) {
    int idx = u * 256 + t8;
    int d0 = (idx & 31) * 2;
    int s0 = (idx >> 5) * 4;
    vs_d[u] = d0;
    vs_s[u] = s0;
    vs_off[u] = (((s0 >> 3) ^ ((d0 >> 1) & 7)) * 8) + (s0 & 7);
  }

  uint32_t vreg[2][4];

  // ---- prologue: DMA K tile 0 of this group's range; prefetch V tile 0 ----
#pragma unroll
  for (int it = 0; it < 2; ++it)
    gl2lds16(kbase + kq_off[it], Ksg + (it * 256 + wq * 64) * 8);
#pragma unroll
  for (int u = 0; u < 2; ++u)
#pragma unroll
    for (int j = 0; j < 4; ++j)
      vreg[u][j] = *(const uint32_t*)(vbase + (size_t)(vs_s[u] + j) * NQKV + vs_d[u]);

  const f32x16 zero16 = {0.f,0.f,0.f,0.f,0.f,0.f,0.f,0.f,0.f,0.f,0.f,0.f,0.f,0.f,0.f,0.f};
  f32x16 oacc[2][2];                    // [dt][q-subblock]
  oacc[0][0] = zero16; oacc[0][1] = zero16;
  oacc[1][0] = zero16; oacc[1][1] = zero16;
  f32x2 psA = {0.f, 0.f}, psB = {0.f, 0.f};
  const float c2 = 0.125f * 1.44269504088896341f;   // scale * log2(e)

  for (int kt = 0; kt < 16; ++kt) {
    const int buf = kt & 1;
    // ---- write staged V regs to LDS (swizzled transpose, v_perm pack) ----
#pragma unroll
    for (int u = 0; u < 2; ++u) {
      int d0 = vs_d[u];
      uint32_t lo0 = __builtin_amdgcn_perm(vreg[u][1], vreg[u][0], 0x05040100u);
      uint32_t lo1 = __builtin_amdgcn_perm(vreg[u][3], vreg[u][2], 0x05040100u);
      uint32_t hi0 = __builtin_amdgcn_perm(vreg[u][1], vreg[u][0], 0x07060302u);
      uint32_t hi1 = __builtin_amdgcn_perm(vreg[u][3], vreg[u][2], 0x07060302u);
      u32x2 lov = {lo0, lo1}, hiv = {hi0, hi1};
      *(u32x2*)&Vsg[buf * 4096 + (d0 + 0) * 64 + vs_off[u]] = lov;
      *(u32x2*)&Vsg[buf * 4096 + (d0 + 1) * 64 + vs_off[u]] = hiv;
    }
    __syncthreads();

    // ---- async K DMA for NEXT tile into buf^1 ----
    {
      int ktn = (kt + 1 < 16) ? kt + 1 : 15;
      const bf16* kb = kbase + (size_t)ktn * 64 * NQKV;
#pragma unroll
      for (int it = 0; it < 2; ++it)
        gl2lds16(kb + kq_off[it], Ksg + (buf ^ 1) * 4096 + (it * 256 + wq * 64) * 8);
    }
    // ---- V register prefetch for next tile ----
    {
      int ktn = (kt + 1 < 16) ? kt + 1 : 15;
      const bf16* vb = vbase + (size_t)ktn * 64 * NQKV;
#pragma unroll
      for (int u = 0; u < 2; ++u)
#pragma unroll
        for (int j = 0; j < 4; ++j)
          vreg[u][j] = *(const uint32_t*)(vb + (size_t)(vs_s[u] + j) * NQKV + vs_d[u]);
    }

    // ---- per 32k-half: S^T = K.Q^T for BOTH q-subblocks (kf reused) ----
#pragma unroll
    for (int kk = 0; kk < 2; ++kk) {
      f32x16 sA = zero16, sB = zero16;
      int srow = kk * 32 + l31;
      int swz  = (srow & 7) * 8;
      __builtin_amdgcn_s_setprio(1);
#pragma unroll
      for (int c = 0; c < 4; ++c) {
        bf16x8 kf = *(const bf16x8*)&Ksg[buf * 4096 + srow * 64 + ((c * 16 + hi8) ^ swz)];
        sA = __builtin_amdgcn_mfma_f32_32x32x16_bf16(kf, qfA[c], sA, 0, 0, 0);
        sB = __builtin_amdgcn_mfma_f32_32x32x16_bf16(kf, qfB[c], sB, 0, 0, 0);
      }
      __builtin_amdgcn_s_setprio(0);

      uint32_t Q8a[8], Q8b[8];
#pragma unroll
      for (int i = 0; i < 8; ++i) {
        f32x2 sva, svb;
        sva[0] = sA[2 * i]; sva[1] = sA[2 * i + 1];
        svb[0] = sB[2 * i]; svb[1] = sB[2 * i + 1];
        f32x2 ta = sva * c2 - 16.0f;                 // v_pk_fma_f32
        f32x2 tb = svb * c2 - 16.0f;
        float a0 = __builtin_amdgcn_exp2f(ta[0]);
        float a1 = __builtin_amdgcn_exp2f(ta[1]);
        float b0 = __builtin_amdgcn_exp2f(tb[0]);
        float b1 = __builtin_amdgcn_exp2f(tb[1]);
        psA += (f32x2){a0, a1};
        psB += (f32x2){b0, b1};
        Q8a[i] = pkbf16(a0, a1);
        Q8b[i] = pkbf16(b0, b1);
      }

#pragma unroll
      for (int mh = 0; mh < 2; ++mh) {
        const int m = kk * 2 + mh, bq = mh * 4;
        u32x4 pda, pdb;
#if __has_builtin(__builtin_amdgcn_permlane32_swap)
        u32x2 wa0 = __builtin_amdgcn_permlane32_swap(Q8a[bq],     Q8a[bq + 2], false, false);
        u32x2 wa1 = __builtin_amdgcn_permlane32_swap(Q8a[bq + 1], Q8a[bq + 3], false, false);
        pda[0] = wa0[0]; pda[1] = wa1[0]; pda[2] = wa0[1]; pda[3] = wa1[1];
        u32x2 wb0 = __builtin_amdgcn_permlane32_swap(Q8b[bq],     Q8b[bq + 2], false, false);
        u32x2 wb1 = __builtin_amdgcn_permlane32_swap(Q8b[bq + 1], Q8b[bq + 3], false, false);
        pdb[0] = wb0[0]; pdb[1] = wb1[0]; pdb[2] = wb0[1]; pdb[3] = wb1[1];
#else
        {
          uint32_t s0 = e ? Q8a[bq]     : Q8a[bq + 2];
          uint32_t s1 = e ? Q8a[bq + 1] : Q8a[bq + 3];
          uint32_t r0 = __shfl_xor(s0, 32);
          uint32_t r1 = __shfl_xor(s1, 32);
          pda[0] = e ? r0 : Q8a[bq];
          pda[1] = e ? r1 : Q8a[bq + 1];
          pda[2] = e ? Q8a[bq + 2] : r0;
          pda[3] = e ? Q8a[bq + 3] : r1;
        }
        {
          uint32_t s0 = e ? Q8b[bq]     : Q8b[bq + 2];
          uint32_t s1 = e ? Q8b[bq + 1] : Q8b[bq + 3];
          uint32_t r0 = __shfl_xor(s0, 32);
          uint32_t r1 = __shfl_xor(s1, 32);
          pdb[0] = e ? r0 : Q8b[bq];
          pdb[1] = e ? r1 : Q8b[bq + 1];
          pdb[2] = e ? Q8b[bq + 2] : r0;
          pdb[3] = e ? Q8b[bq + 3] : r1;
        }
#endif
        bf16x8 pfa = __builtin_bit_cast(bf16x8, pda);
        bf16x8 pfb = __builtin_bit_cast(bf16x8, pdb);
        __builtin_amdgcn_s_setprio(1);
#pragma unroll
        for (int dt = 0; dt < 2; ++dt) {
          int drow = dt * 32 + l31;
          int swv  = (drow >> 1) & 7;
          bf16x8 vf = *(const bf16x8*)&Vsg[buf * 4096 + drow * 64 + (((m * 2 + e) ^ swv) * 8)];
          oacc[dt][0] = __builtin_amdgcn_mfma_f32_32x32x16_bf16(vf, pfa, oacc[dt][0], 0, 0, 0);
          oacc[dt][1] = __builtin_amdgcn_mfma_f32_32x32x16_bf16(vf, pfb, oacc[dt][1], 0, 0, 0);
        }
        __builtin_amdgcn_s_setprio(0);
      }
    }
  }

  // per-q totals for this group's KV half (lanes l31 & l31+32 share a column)
  float lsumA = psA[0] + psA[1];
  float lsumB = psB[0] + psB[1];
  lsumA += __shfl_xor(lsumA, 32);
  lsumB += __shfl_xor(lsumB, 32);

  // ================= cross-group combine epilogue =================
  float* const S4 = (float*)smem;

  // E1: lsum exchange ([2][256] f32 = 2 KB at smem base)
  __syncthreads();                       // all K/V reads done
  if (e == 0) {
    S4[grp * 256 + wq * 64 + l31]      = lsumA;
    S4[grp * 256 + wq * 64 + 32 + l31] = lsumB;
  }
  __syncthreads();
  float invA = 0.f, invB = 0.f;
  if (grp == 1) {
    invA = 1.f / (S4[wq * 64 + l31]      + lsumA);
    invB = 1.f / (S4[wq * 64 + 32 + l31] + lsumB);
  }
  __syncthreads();                       // before Osum overwrites Ls

  // E2: group 0 writes O^T partial f32 into its wave's 16 KB slice.
  // slice wq: rows l=0..63 (local q), 64 f32 each; chunk c = d/4 (0..15),
  // stored at c ^ (l&15). Lane (l31,e) holds d = dt*32+8*hi+4*e -> c = dt*8+2*hi+e.
  if (grp == 0) {
#pragma unroll
    for (int dt = 0; dt < 2; ++dt)
#pragma unroll
      for (int qs = 0; qs < 2; ++qs)
#pragma unroll
        for (int hi = 0; hi < 4; ++hi) {
          int l = qs * 32 + l31;
          int c = (dt * 8 + 2 * hi + e) ^ (l & 15);
          f32x4 v4;
          v4[0] = oacc[dt][qs][hi * 4 + 0];
          v4[1] = oacc[dt][qs][hi * 4 + 1];
          v4[2] = oacc[dt][qs][hi * 4 + 2];
          v4[3] = oacc[dt][qs][hi * 4 + 3];
          *(f32x4*)&S4[wq * 4096 + l * 64 + c * 4] = v4;
        }
  }
  __syncthreads();

  // E3: group 1 reads partial, adds own, normalizes, writes bf16 Os into the
  // SECOND half of its slice (bytes 8..16 KB = Osum rows 32..63). Order:
  // qs=1 (read rows 32..63) first, then its Os writes land in rows 48..63
  // region already consumed; qs=0 reads rows 0..31 (untouched), writes rows
  // 32..47 region (consumed in qs=1 phase). Per-wave LDS FIFO keeps order.
  if (grp == 1) {
#pragma unroll
    for (int qs = 1; qs >= 0; --qs) {
      int l = qs * 32 + l31;
      float inv = qs ? invB : invA;
      f32x4 po[8];
#pragma unroll
      for (int dt = 0; dt < 2; ++dt)
#pragma unroll
        for (int hi = 0; hi < 4; ++hi) {
          int c = (dt * 8 + 2 * hi + e) ^ (l & 15);
          po[dt * 4 + hi] = *(const f32x4*)&S4[wq * 4096 + l * 64 + c * 4];
        }
#pragma unroll
      for (int dt = 0; dt < 2; ++dt)
#pragma unroll
        for (int hi = 0; hi < 4; ++hi) {
          bf16x4 ov;
#pragma unroll
          for (int j = 0; j < 4; ++j)
            ov[j] = (bf16)((po[dt * 4 + hi][j] + oacc[dt][qs][hi * 4 + j]) * inv);
          int hc = (dt * 8 + 2 * hi + e) ^ (l & 15);
          *(bf16x4*)&smem[wq * 8192 + 4096 + l * 64 + hc * 4] = ov;
        }
    }
  }
  __syncthreads();

  // E4: coalesced store. Os row for global q: slice q>>6, local l=q&63, at
  // bf16 element (q>>6)*8192 + 4096 + l*64, half-chunk hc=d/4 at hc^(l&15).
#pragma unroll
  for (int it = 0; it < 4; ++it) {
    int idx = it * 512 + tid;            // 0..2047
    int q = idx >> 3, k8 = idx & 7;
    int ws_ = q >> 6, l = q & 63;
    int base = ws_ * 8192 + 4096 + l * 64;
    int h0 = (2 * k8)     ^ (l & 15);
    int h1 = (2 * k8 + 1) ^ (l & 15);
    bf16x4 a = *(const bf16x4*)&smem[base + h0 * 4];
    bf16x4 bb = *(const bf16x4*)&smem[base + h1 * 4];
    bf16x8 t;
    t[0] = a[0]; t[1] = a[1]; t[2] = a[2]; t[3] = a[3];
    t[4] = bb[0]; t[5] = bb[1]; t[6] = bb[2]; t[7] = bb[3];
    *(bf16x8*)&out[(rowb + q0 + q) * D_ + h * HD_ + k8 * 8] = t;
  }
}

extern "C" void kernel_launch(void* const* d_in, const int* in_sizes, int n_in,
                              void* d_out, int out_size, void* d_ws, size_t ws_size,
                              hipStream_t stream) {
  const float* x     = (const float*)d_in[0];
  const float* w_qkv = (const float*)d_in[1];
  const float* b_qkv = (const float*)d_in[2];
  const float* w_out = (const float*)d_in[3];
  const float* b_out = (const float*)d_in[4];
  float* out = (float*)d_out;

  char* ws = (char*)d_ws;
  bf16* xb    = (bf16*)(ws);                         // 16 MB
  bf16* wqkvT = (bf16*)(ws + (size_t)16777216);      //  6 MB
  bf16* woutT = (bf16*)(ws + (size_t)23068672);      //  2 MB
  bf16* qkvb  = (bf16*)(ws + (size_t)25165824);      // 48 MB
  bf16* attnb = (bf16*)(ws + (size_t)75497472);      // 16 MB

  cast_f32_bf16<<<(M_ * D_ / 4 + 255) / 256, 256, 0, stream>>>(x, xb, M_ * D_ / 4);
  transpose_cast<<<dim3(NQKV / 32, D_ / 32), dim3(32, 8), 0, stream>>>(w_qkv, wqkvT, D_, NQKV);
  transpose_cast<<<dim3(D_ / 32, D_ / 32), dim3(32, 8), 0, stream>>>(w_out, woutT, D_, D_);

  gemm_bt_wide<<<(M_ / 128) * (NQKV / 256), 256, 0, stream>>>(
      xb, wqkvT, b_qkv, qkvb, M_, NQKV, D_);

  flash_attn<<<B_ * H_ * (S_ / 256), 512, 0, stream>>>(qkvb, attnb);

  gemm_bt<false><<<(M_ / 128) * (D_ / 128), 256, 0, stream>>>(
      attnb, woutT, b_out, (void*)out, M_, D_, D_);
}

// Round 6
// 307.179 us; speedup vs baseline: 1.6060x; 1.6060x over previous
//
#include <hip/hip_runtime.h>
#include <cstdint>
#include <cstddef>

// ---- problem constants ----
#define B_    4
#define S_    2048
#define D_    1024
#define H_    16
#define HD_   64
#define M_    8192      // B_*S_
#define NQKV  3072

typedef __bf16 bf16;
typedef __bf16 bf16x4 __attribute__((ext_vector_type(4)));
typedef __bf16 bf16x8 __attribute__((ext_vector_type(8)));
typedef float  f32x2  __attribute__((ext_vector_type(2)));
typedef float  f32x4  __attribute__((ext_vector_type(4)));
typedef float  f32x16 __attribute__((ext_vector_type(16)));
typedef uint32_t u32x2 __attribute__((ext_vector_type(2)));
typedef uint32_t u32x4 __attribute__((ext_vector_type(4)));

// async global->LDS, 16B per lane. LDS dest is wave-uniform base + lane*16.
__device__ __forceinline__ void gl2lds16(const void* g, void* l) {
  __builtin_amdgcn_global_load_lds(
      (__attribute__((address_space(1))) void*)(uintptr_t)g,
      (__attribute__((address_space(3))) void*)l, 16, 0, 0);
}

__device__ __forceinline__ uint32_t pkbf16(float a, float b) {
  union { bf16 h[2]; uint32_t u; } z;
  z.h[0] = (bf16)a; z.h[1] = (bf16)b;
  return z.u;
}

// ---- prep: fp32 -> bf16 cast (x) ----
__global__ __launch_bounds__(256) void cast_f32_bf16(const float* __restrict__ in,
                                                     bf16* __restrict__ out, int n4) {
  int i = blockIdx.x * 256 + threadIdx.x;
  if (i >= n4) return;
  float4 v = ((const float4*)in)[i];
  bf16x4 o;
  o[0] = (bf16)v.x; o[1] = (bf16)v.y; o[2] = (bf16)v.z; o[3] = (bf16)v.w;
  ((bf16x4*)out)[i] = o;
}

// ---- prep: transpose + cast: in [R,C] fp32 -> out [C,R] bf16 ----
__global__ __launch_bounds__(256) void transpose_cast(const float* __restrict__ in,
                                                      bf16* __restrict__ out, int R, int C) {
  __shared__ float tile[32][33];
  int bx = blockIdx.x * 32, by = blockIdx.y * 32;
  int tx = threadIdx.x, ty = threadIdx.y;
#pragma unroll
  for (int i = 0; i < 32; i += 8)
    tile[ty + i][tx] = in[(size_t)(by + ty + i) * C + bx + tx];
  __syncthreads();
#pragma unroll
  for (int i = 0; i < 32; i += 8)
    out[(size_t)(bx + ty + i) * R + by + tx] = (bf16)tile[tx][ty + i];
}

// ---- 128x128 GEMM w/ XCD super-tiling: C[M,N] = A[M,K]*Bt[N,K]^T + bias ----
template <bool OUT_BF16>
__global__ __launch_bounds__(256) void gemm_bt(const bf16* __restrict__ A,
                                               const bf16* __restrict__ Bt,
                                               const float* __restrict__ bias,
                                               void* __restrict__ Cptr,
                                               int M, int N, int K) {
  __shared__ __align__(16) bf16 As[128 * 64];
  __shared__ __align__(16) bf16 Bs[128 * 64];
  const int tid  = threadIdx.x;
  const int lane = tid & 63, w = tid >> 6;
  const int lo   = lane & 15, quad = lane >> 4;
  const int xcd = blockIdx.x & 7, g = blockIdx.x >> 3;
  const int mi  = g & 7,          n = g >> 3;
  const int bm  = (xcd * 8 + mi) * 128, bn = n * 128;
  const int wm = (w >> 1) * 64,    wn = (w & 1) * 64;

  f32x4 acc[4][4];
  const f32x4 zero = {0.f, 0.f, 0.f, 0.f};
#pragma unroll
  for (int i = 0; i < 4; ++i)
#pragma unroll
    for (int j = 0; j < 4; ++j) acc[i][j] = zero;

  for (int k0 = 0; k0 < K; k0 += 64) {
#pragma unroll
    for (int c = 0; c < 4; ++c) {
      int seg = c * 4 + w;
      int idx = seg * 512 + lane * 8;
      int row = idx >> 6, col = idx & 63;
      gl2lds16(A  + (size_t)(bm + row) * K + k0 + col, As + seg * 512);
      gl2lds16(Bt + (size_t)(bn + row) * K + k0 + col, Bs + seg * 512);
    }
    __syncthreads();
#pragma unroll
    for (int ks = 0; ks < 2; ++ks) {
      bf16x8 av[4], bv[4];
#pragma unroll
      for (int i = 0; i < 4; ++i)
        av[i] = *(const bf16x8*)&As[(wm + i * 16 + lo) * 64 + ks * 32 + quad * 8];
#pragma unroll
      for (int j = 0; j < 4; ++j)
        bv[j] = *(const bf16x8*)&Bs[(wn + j * 16 + lo) * 64 + ks * 32 + quad * 8];
#pragma unroll
      for (int i = 0; i < 4; ++i)
#pragma unroll
        for (int j = 0; j < 4; ++j)
          acc[i][j] = __builtin_amdgcn_mfma_f32_16x16x32_bf16(av[i], bv[j], acc[i][j], 0, 0, 0);
    }
    __syncthreads();
  }
#pragma unroll
  for (int j = 0; j < 4; ++j) {
    int cg = bn + wn + j * 16 + lo;
    float bsv = bias[cg];
#pragma unroll
    for (int i = 0; i < 4; ++i) {
      int rg = bm + wm + i * 16 + quad * 4;
#pragma unroll
      for (int r = 0; r < 4; ++r) {
        float v = acc[i][j][r] + bsv;
        if (OUT_BF16) ((bf16*)Cptr)[(size_t)(rg + r) * N + cg] = (bf16)v;
        else          ((float*)Cptr)[(size_t)(rg + r) * N + cg] = v;
      }
    }
  }
}

// ---- 128x256 GEMM (qkv) ----
__global__ __launch_bounds__(256, 2) void gemm_bt_wide(const bf16* __restrict__ A,
                                                       const bf16* __restrict__ Bt,
                                                       const float* __restrict__ bias,
                                                       bf16* __restrict__ Cptr,
                                                       int M, int N, int K) {
  __shared__ __align__(16) bf16 As[128 * 64];   // 16 KB
  __shared__ __align__(16) bf16 Bs[256 * 64];   // 32 KB
  const int tid  = threadIdx.x;
  const int lane = tid & 63, w = tid >> 6;
  const int lo   = lane & 15, quad = lane >> 4;
  const int xcd = blockIdx.x & 7, g = blockIdx.x >> 3;
  const int mi  = g & 7,          n = g >> 3;
  const int bm  = (xcd * 8 + mi) * 128, bn = n * 256;
  const int wm = (w >> 1) * 64,    wn = (w & 1) * 128;

  f32x4 acc[4][8];
  const f32x4 zero = {0.f, 0.f, 0.f, 0.f};
#pragma unroll
  for (int i = 0; i < 4; ++i)
#pragma unroll
    for (int j = 0; j < 8; ++j) acc[i][j] = zero;

  for (int k0 = 0; k0 < K; k0 += 64) {
#pragma unroll
    for (int c = 0; c < 4; ++c) {
      int seg = c * 4 + w;
      int idx = seg * 512 + lane * 8;
      int row = idx >> 6, col = idx & 63;
      gl2lds16(A + (size_t)(bm + row) * K + k0 + col, As + seg * 512);
    }
#pragma unroll
    for (int c = 0; c < 8; ++c) {
      int seg = c * 4 + w;
      int idx = seg * 512 + lane * 8;
      int row = idx >> 6, col = idx & 63;
      gl2lds16(Bt + (size_t)(bn + row) * K + k0 + col, Bs + seg * 512);
    }
    __syncthreads();
#pragma unroll
    for (int ks = 0; ks < 2; ++ks) {
      bf16x8 av[4], bv[8];
#pragma unroll
      for (int i = 0; i < 4; ++i)
        av[i] = *(const bf16x8*)&As[(wm + i * 16 + lo) * 64 + ks * 32 + quad * 8];
#pragma unroll
      for (int j = 0; j < 8; ++j)
        bv[j] = *(const bf16x8*)&Bs[(wn + j * 16 + lo) * 64 + ks * 32 + quad * 8];
#pragma unroll
      for (int i = 0; i < 4; ++i)
#pragma unroll
        for (int j = 0; j < 8; ++j)
          acc[i][j] = __builtin_amdgcn_mfma_f32_16x16x32_bf16(av[i], bv[j], acc[i][j], 0, 0, 0);
    }
    __syncthreads();
  }
#pragma unroll
  for (int j = 0; j < 8; ++j) {
    int cg = bn + wn + j * 16 + lo;
    float bsv = bias[cg];
#pragma unroll
    for (int i = 0; i < 4; ++i) {
      int rg = bm + wm + i * 16 + quad * 4;
#pragma unroll
      for (int r = 0; r < 4; ++r)
        Cptr[(size_t)(rg + r) * N + cg] = (bf16)(acc[i][j][r] + bsv);
    }
  }
}

// ---- flash attention v15: v11 loop + cross-BLOCK KV split ----
// R5 lesson (twice now): this compute needs ~170 unified regs -> max 3
// waves/SIMD; >=4 waves/SIMD launch bounds spill catastrophically (v13:
// VGPR 64 arch at 128-cap, 766 MB scratch FETCH). v11's resources (32 KB
// LDS, ~168 regs) allow 3 blocks/CU -- the GRID (512 = 2/CU) is the binding
// occupancy limit. v15 keeps v11's per-wave structure VERBATIM and splits
// the 32 KV tiles across 2 blocks (grid 1024 -> 3 blocks/CU, 12 waves/CU).
// Fixed-exponent softmax (p = 2^(s*c2-16)) makes partials additive: each
// part writes O^T partial (f32, 64 MB) + lsum (1 MB); a combine kernel does
// (o0+o1)/(l0+l1) -> bf16 attnb. SPLIT=0 instantiation = v11 single-pass
// fallback if ws_size is too small for the partial buffers.
// NOTE for counter reading: flash WRITE_SIZE ~66 MB is EXPECTED (opart
// data); spill signature would be VGPR=64 + FETCH >> 100 MB.
template <int SPLIT>
__global__ __launch_bounds__(256, 2) void flash_attn_k(const bf16* __restrict__ qkv,
                                                       bf16* __restrict__ out,
                                                       float* __restrict__ opart,
                                                       float* __restrict__ lpart) {
  // 32 KB: K double-buffer (16K) + V double-buffer (16K); full-path epilogue reuses as O
  __shared__ __align__(16) bf16 smem[16384];
  bf16* const Ksm = smem;          // [2][64*64], chunk-swizzled rows
  bf16* const Vsm = smem + 8192;   // [2][64*64], [d][s] chunk-swizzled

  const int tid  = threadIdx.x;
  const int lane = tid & 63, wq = tid >> 6;
  const int l31  = lane & 31;
  const int e    = lane >> 5;           // hi1
  const int hi8  = e * 8, hi4 = e * 4;

  const int bid = blockIdx.x;
  const int ob  = SPLIT ? (bid >> 1) : bid;
  const int grp = SPLIT ? (bid & 1) : 0;
  const int NT  = SPLIT ? 16 : 32;      // KV tiles this block processes
  const int qb  = ob >> 6;              // 0..7 (256 q each)
  const int bh  = ob & 63;
  const int h   = bh & 15;
  const int b   = bh >> 4;
  const int q0  = qb * 256;
  const size_t rowb = (size_t)b * S_;
  const bf16* qbase = qkv + rowb * NQKV + h * HD_;
  const bf16* kbase = qbase + D_     + (size_t)(grp * 16) * 64 * NQKV;
  const bf16* vbase = qbase + 2 * D_ + (size_t)(grp * 16) * 64 * NQKV;

  // ---- Q fragments for the wave's TWO q-subblocks (loop-invariant) ----
  bf16x8 qfA[4], qfB[4];
  {
    const bf16* qrow0 = qbase + (size_t)(q0 + wq * 64 + l31) * NQKV;
    const bf16* qrow1 = qrow0 + (size_t)32 * NQKV;
#pragma unroll
    for (int c = 0; c < 4; ++c) {
      qfA[c] = *(const bf16x8*)(qrow0 + c * 16 + hi8);
      qfB[c] = *(const bf16x8*)(qrow1 + c * 16 + hi8);
    }
  }

  // ---- K DMA indices: chunk ci = it*256+tid -> global (s, x), LDS contiguous ----
  int kq_off[2];
#pragma unroll
  for (int it = 0; it < 2; ++it) {
    int ci = it * 256 + tid;
    int s  = ci >> 3;
    int x  = (ci & 7) ^ (s & 7);
    kq_off[it] = s * NQKV + x * 8;
  }
  // ---- V staging indices ----
  int vs_d[2], vs_s[2], vs_off[2];
#pragma unroll
  for (int u = 0; u < 2; ++u) {
    int idx = u * 256 + tid;
    int d0 = (idx & 31) * 2;
    int s0 = (idx >> 5) * 4;
    vs_d[u] = d0;
    vs_s[u] = s0;
    vs_off[u] = (((s0 >> 3) ^ ((d0 >> 1) & 7)) * 8) + (s0 & 7);
  }

  uint32_t vreg[2][4];

  // ---- prologue: DMA K tile 0 into buf0; prefetch V tile 0 regs ----
#pragma unroll
  for (int it = 0; it < 2; ++it)
    gl2lds16(kbase + kq_off[it], Ksm + (it * 256 + wq * 64) * 8);
#pragma unroll
  for (int u = 0; u < 2; ++u)
#pragma unroll
    for (int j = 0; j < 4; ++j)
      vreg[u][j] = *(const uint32_t*)(vbase + (size_t)(vs_s[u] + j) * NQKV + vs_d[u]);

  const f32x16 zero16 = {0.f,0.f,0.f,0.f,0.f,0.f,0.f,0.f,0.f,0.f,0.f,0.f,0.f,0.f,0.f,0.f};
  f32x16 oacc[2][2];                    // [dt][q-subblock]
  oacc[0][0] = zero16; oacc[0][1] = zero16;
  oacc[1][0] = zero16; oacc[1][1] = zero16;
  f32x2 psA = {0.f, 0.f}, psB = {0.f, 0.f};
  const float c2 = 0.125f * 1.44269504088896341f;   // scale * log2(e)

  for (int kt = 0; kt < NT; ++kt) {
    const int buf = kt & 1;
    // ---- write staged V regs to LDS (swizzled transpose, v_perm pack) ----
#pragma unroll
    for (int u = 0; u < 2; ++u) {
      int d0 = vs_d[u];
      uint32_t lo0 = __builtin_amdgcn_perm(vreg[u][1], vreg[u][0], 0x05040100u);
      uint32_t lo1 = __builtin_amdgcn_perm(vreg[u][3], vreg[u][2], 0x05040100u);
      uint32_t hi0 = __builtin_amdgcn_perm(vreg[u][1], vreg[u][0], 0x07060302u);
      uint32_t hi1 = __builtin_amdgcn_perm(vreg[u][3], vreg[u][2], 0x07060302u);
      u32x2 lov = {lo0, lo1}, hiv = {hi0, hi1};
      *(u32x2*)&Vsm[buf * 4096 + (d0 + 0) * 64 + vs_off[u]] = lov;
      *(u32x2*)&Vsm[buf * 4096 + (d0 + 1) * 64 + vs_off[u]] = hiv;
    }
    __syncthreads();

    // ---- async K DMA for NEXT tile into buf^1 (drained by next barrier) ----
    {
      int ktn = (kt + 1 < NT) ? kt + 1 : NT - 1;
      const bf16* kb = kbase + (size_t)ktn * 64 * NQKV;
#pragma unroll
      for (int it = 0; it < 2; ++it)
        gl2lds16(kb + kq_off[it], Ksm + (buf ^ 1) * 4096 + (it * 256 + wq * 64) * 8);
    }
    // ---- V register prefetch for next tile ----
    {
      int ktn = (kt + 1 < NT) ? kt + 1 : NT - 1;
      const bf16* vb = vbase + (size_t)ktn * 64 * NQKV;
#pragma unroll
      for (int u = 0; u < 2; ++u)
#pragma unroll
        for (int j = 0; j < 4; ++j)
          vreg[u][j] = *(const uint32_t*)(vb + (size_t)(vs_s[u] + j) * NQKV + vs_d[u]);
    }

    // ---- per 32k-half: S^T = K.Q^T for BOTH q-subblocks (kf reused) ----
#pragma unroll
    for (int kk = 0; kk < 2; ++kk) {
      f32x16 sA = zero16, sB = zero16;
      int srow = kk * 32 + l31;
      int swz  = (srow & 7) * 8;
      __builtin_amdgcn_s_setprio(1);
#pragma unroll
      for (int c = 0; c < 4; ++c) {
        bf16x8 kf = *(const bf16x8*)&Ksm[buf * 4096 + srow * 64 + ((c * 16 + hi8) ^ swz)];
        sA = __builtin_amdgcn_mfma_f32_32x32x16_bf16(kf, qfA[c], sA, 0, 0, 0);
        sB = __builtin_amdgcn_mfma_f32_32x32x16_bf16(kf, qfB[c], sB, 0, 0, 0);
      }
      __builtin_amdgcn_s_setprio(0);

      uint32_t Q8a[8], Q8b[8];
#pragma unroll
      for (int i = 0; i < 8; ++i) {
        f32x2 sva, svb;
        sva[0] = sA[2 * i]; sva[1] = sA[2 * i + 1];
        svb[0] = sB[2 * i]; svb[1] = sB[2 * i + 1];
        f32x2 ta = sva * c2 - 16.0f;                 // v_pk_fma_f32
        f32x2 tb = svb * c2 - 16.0f;
        float a0 = __builtin_amdgcn_exp2f(ta[0]);
        float a1 = __builtin_amdgcn_exp2f(ta[1]);
        float b0 = __builtin_amdgcn_exp2f(tb[0]);
        float b1 = __builtin_amdgcn_exp2f(tb[1]);
        psA += (f32x2){a0, a1};
        psB += (f32x2){b0, b1};
        Q8a[i] = pkbf16(a0, a1);
        Q8b[i] = pkbf16(b0, b1);
      }

#pragma unroll
      for (int mh = 0; mh < 2; ++mh) {
        const int m = kk * 2 + mh, bq = mh * 4;
        u32x4 pda, pdb;
#if __has_builtin(__builtin_amdgcn_permlane32_swap)
        u32x2 wa0 = __builtin_amdgcn_permlane32_swap(Q8a[bq],     Q8a[bq + 2], false, false);
        u32x2 wa1 = __builtin_amdgcn_permlane32_swap(Q8a[bq + 1], Q8a[bq + 3], false, false);
        pda[0] = wa0[0]; pda[1] = wa1[0]; pda[2] = wa0[1]; pda[3] = wa1[1];
        u32x2 wb0 = __builtin_amdgcn_permlane32_swap(Q8b[bq],     Q8b[bq + 2], false, false);
        u32x2 wb1 = __builtin_amdgcn_permlane32_swap(Q8b[bq + 1], Q8b[bq + 3], false, false);
        pdb[0] = wb0[0]; pdb[1] = wb1[0]; pdb[2] = wb0[1]; pdb[3] = wb1[1];
#else
        {
          uint32_t s0 = e ? Q8a[bq]     : Q8a[bq + 2];
          uint32_t s1 = e ? Q8a[bq + 1] : Q8a[bq + 3];
          uint32_t r0 = __shfl_xor(s0, 32);
          uint32_t r1 = __shfl_xor(s1, 32);
          pda[0] = e ? r0 : Q8a[bq];
          pda[1] = e ? r1 : Q8a[bq + 1];
          pda[2] = e ? Q8a[bq + 2] : r0;
          pda[3] = e ? Q8a[bq + 3] : r1;
        }
        {
          uint32_t s0 = e ? Q8b[bq]     : Q8b[bq + 2];
          uint32_t s1 = e ? Q8b[bq + 1] : Q8b[bq + 3];
          uint32_t r0 = __shfl_xor(s0, 32);
          uint32_t r1 = __shfl_xor(s1, 32);
          pdb[0] = e ? r0 : Q8b[bq];
          pdb[1] = e ? r1 : Q8b[bq + 1];
          pdb[2] = e ? Q8b[bq + 2] : r0;
          pdb[3] = e ? Q8b[bq + 3] : r1;
        }
#endif
        bf16x8 pfa = __builtin_bit_cast(bf16x8, pda);
        bf16x8 pfb = __builtin_bit_cast(bf16x8, pdb);
        __builtin_amdgcn_s_setprio(1);
#pragma unroll
        for (int dt = 0; dt < 2; ++dt) {
          int drow = dt * 32 + l31;
          int swv  = (drow >> 1) & 7;
          bf16x8 vf = *(const bf16x8*)&Vsm[buf * 4096 + drow * 64 + (((m * 2 + e) ^ swv) * 8)];
          oacc[dt][0] = __builtin_amdgcn_mfma_f32_32x32x16_bf16(vf, pfa, oacc[dt][0], 0, 0, 0);
          oacc[dt][1] = __builtin_amdgcn_mfma_f32_32x32x16_bf16(vf, pfb, oacc[dt][1], 0, 0, 0);
        }
        __builtin_amdgcn_s_setprio(0);
      }
    }
  }

  float lsumA = psA[0] + psA[1];
  float lsumB = psB[0] + psB[1];
  lsumA += __shfl_xor(lsumA, 32);
  lsumB += __shfl_xor(lsumB, 32);

  if (SPLIT) {
    // ---- partial epilogue: direct f32 stores, no LDS, no normalize ----
    // lane (l31,e) holds q = wq*64 + qs*32 + l31, d = dt*32 + 8g + 4e + jj
    float* obase = opart + (size_t)bid * (256 * 64);
    if (e == 0) {
      lpart[bid * 256 + wq * 64 + l31]      = lsumA;
      lpart[bid * 256 + wq * 64 + 32 + l31] = lsumB;
    }
#pragma unroll
    for (int qs = 0; qs < 2; ++qs) {
      float* oq = obase + (size_t)(wq * 64 + qs * 32 + l31) * 64;
#pragma unroll
      for (int dt = 0; dt < 2; ++dt)
#pragma unroll
        for (int g = 0; g < 4; ++g) {
          f32x4 v4;
          v4[0] = oacc[dt][qs][g * 4 + 0];
          v4[1] = oacc[dt][qs][g * 4 + 1];
          v4[2] = oacc[dt][qs][g * 4 + 2];
          v4[3] = oacc[dt][qs][g * 4 + 3];
          *(f32x4*)&oq[dt * 32 + g * 8 + e * 4] = v4;
        }
    }
  } else {
    // ---- v11 full epilogue: O^T/lsum -> LDS (chunk-swizzled) -> 16B stores ----
    __syncthreads();                       // all Ks/Vs reads done; safe to reuse
    bf16* Os = smem;                       // [256][64] bf16, chunk-XOR ((row>>1)&7)
    {
      float invA = 1.f / lsumA;
      float invB = 1.f / lsumB;
#pragma unroll
      for (int qs = 0; qs < 2; ++qs) {
        float inv = qs ? invB : invA;
        int ql = wq * 64 + qs * 32 + l31;
        int swO = (ql >> 1) & 7;
#pragma unroll
        for (int dt = 0; dt < 2; ++dt) {
#pragma unroll
          for (int g = 0; g < 4; ++g) {
            bf16x4 ov;
#pragma unroll
            for (int jj = 0; jj < 4; ++jj)
              ov[jj] = (bf16)(oacc[dt][qs][g * 4 + jj] * inv);
            *(bf16x4*)&Os[ql * 64 + (((dt * 4 + g) ^ swO) * 8) + hi4] = ov;
          }
        }
      }
    }
    __syncthreads();
#pragma unroll
    for (int it = 0; it < 8; ++it) {
      int idx = it * 256 + tid;
      int row = idx >> 3, c8 = idx & 7;
      bf16x8 t = *(const bf16x8*)&Os[row * 64 + ((c8 ^ ((row >> 1) & 7)) * 8)];
      *(bf16x8*)&out[(rowb + q0 + row) * D_ + h * HD_ + c8 * 8] = t;
    }
  }
}

// ---- combine: attnb[q, h*64+d] = (o0+o1) / (l0+l1), fully coalesced ----
__global__ __launch_bounds__(256) void combine_parts(const float* __restrict__ opart,
                                                     const float* __restrict__ lpart,
                                                     bf16* __restrict__ out) {
  const int ob = blockIdx.x;             // 0..511
  const int qb = ob >> 6, bh = ob & 63;
  const int h  = bh & 15, b = bh >> 4;
  const int q0 = qb * 256;
  const size_t rowb = (size_t)b * S_;
  const float* o0 = opart + (size_t)(2 * ob) * (256 * 64);
  const float* o1 = o0 + 256 * 64;
  const float* l0 = lpart + (size_t)(2 * ob) * 256;
  const float* l1 = l0 + 256;
  const int tid = threadIdx.x;
#pragma unroll
  for (int rep = 0; rep < 4; ++rep) {
    int flat = rep * 4096 + tid * 16;    // 16 d-elems per thread
    int q = flat >> 6, d0 = flat & 63;
    float inv = 1.f / (l0[q] + l1[q]);
    bf16* dst = out + (rowb + q0 + q) * D_ + h * HD_ + d0;
#pragma unroll
    for (int half = 0; half < 2; ++half) {
      bf16x8 t;
#pragma unroll
      for (int c = 0; c < 2; ++c) {
        f32x4 x = *(const f32x4*)&o0[(size_t)q * 64 + d0 + half * 8 + c * 4];
        f32x4 y = *(const f32x4*)&o1[(size_t)q * 64 + d0 + half * 8 + c * 4];
#pragma unroll
        for (int j = 0; j < 4; ++j)
          t[c * 4 + j] = (bf16)((x[j] + y[j]) * inv);
      }
      *(bf16x8*)&dst[half * 8] = t;
    }
  }
}

extern "C" void kernel_launch(void* const* d_in, const int* in_sizes, int n_in,
                              void* d_out, int out_size, void* d_ws, size_t ws_size,
                              hipStream_t stream) {
  const float* x     = (const float*)d_in[0];
  const float* w_qkv = (const float*)d_in[1];
  const float* b_qkv = (const float*)d_in[2];
  const float* w_out = (const float*)d_in[3];
  const float* b_out = (const float*)d_in[4];
  float* out = (float*)d_out;

  // ws layout (peak 137 MB for the split path):
  //   xb     0 .. 16 MB   (dead after qkv GEMM; attnb overlays it)
  //   wqkvT 16 .. 22 MB   (dead after qkv GEMM)
  //   woutT 22 .. 24 MB   (live till end)
  //   qkvb  24 .. 72 MB   (live till flash done)
  //   opart 72 .. 136 MB  (split path only)
  //   lpart 136 .. 137 MB (split path only)
  char* ws = (char*)d_ws;
  bf16*  xb    = (bf16*)(ws);
  bf16*  attnb = (bf16*)(ws);                          // overlays xb
  bf16*  wqkvT = (bf16*)(ws + (size_t)16777216);
  bf16*  woutT = (bf16*)(ws + (size_t)23068672);
  bf16*  qkvb  = (bf16*)(ws + (size_t)25165824);
  float* opart = (float*)(ws + (size_t)75497472);
  float* lpart = (float*)(ws + (size_t)142606336);
  const size_t WS_NEED_SPLIT = 143654912;              // 137 MB

  cast_f32_bf16<<<(M_ * D_ / 4 + 255) / 256, 256, 0, stream>>>(x, xb, M_ * D_ / 4);
  transpose_cast<<<dim3(NQKV / 32, D_ / 32), dim3(32, 8), 0, stream>>>(w_qkv, wqkvT, D_, NQKV);
  transpose_cast<<<dim3(D_ / 32, D_ / 32), dim3(32, 8), 0, stream>>>(w_out, woutT, D_, D_);

  gemm_bt_wide<<<(M_ / 128) * (NQKV / 256), 256, 0, stream>>>(
      xb, wqkvT, b_qkv, qkvb, M_, NQKV, D_);

  if (ws_size >= WS_NEED_SPLIT) {
    flash_attn_k<1><<<B_ * H_ * (S_ / 256) * 2, 256, 0, stream>>>(qkvb, attnb, opart, lpart);
    combine_parts<<<B_ * H_ * (S_ / 256), 256, 0, stream>>>(opart, lpart, attnb);
  } else {
    flash_attn_k<0><<<B_ * H_ * (S_ / 256), 256, 0, stream>>>(qkvb, attnb, nullptr, nullptr);
  }

  gemm_bt<false><<<(M_ / 128) * (D_ / 128), 256, 0, stream>>>(
      attnb, woutT, b_out, (void*)out, M_, D_, D_);
}

// Round 7
// 273.279 us; speedup vs baseline: 1.8052x; 1.1240x over previous
//
#include <hip/hip_runtime.h>
#include <cstdint>
#include <cstddef>

// ---- problem constants ----
#define B_    4
#define S_    2048
#define D_    1024
#define H_    16
#define HD_   64
#define M_    8192      // B_*S_
#define NQKV  3072

typedef __bf16 bf16;
typedef __bf16 bf16x4 __attribute__((ext_vector_type(4)));
typedef __bf16 bf16x8 __attribute__((ext_vector_type(8)));
typedef float  f32x2  __attribute__((ext_vector_type(2)));
typedef float  f32x4  __attribute__((ext_vector_type(4)));
typedef float  f32x16 __attribute__((ext_vector_type(16)));
typedef uint32_t u32x2 __attribute__((ext_vector_type(2)));
typedef uint32_t u32x4 __attribute__((ext_vector_type(4)));

#define MFMA16(a, b, c) __builtin_amdgcn_mfma_f32_16x16x32_bf16(a, b, c, 0, 0, 0)

// async global->LDS, 16B per lane. LDS dest is wave-uniform base + lane*16.
__device__ __forceinline__ void gl2lds16(const void* g, void* l) {
  __builtin_amdgcn_global_load_lds(
      (__attribute__((address_space(1))) void*)(uintptr_t)g,
      (__attribute__((address_space(3))) void*)l, 16, 0, 0);
}

__device__ __forceinline__ uint32_t pkbf16(float a, float b) {
  union { bf16 h[2]; uint32_t u; } z;
  z.h[0] = (bf16)a; z.h[1] = (bf16)b;
  return z.u;
}

// ---- prep: fp32 -> bf16 cast (x) ----
__global__ __launch_bounds__(256) void cast_f32_bf16(const float* __restrict__ in,
                                                     bf16* __restrict__ out, int n4) {
  int i = blockIdx.x * 256 + threadIdx.x;
  if (i >= n4) return;
  float4 v = ((const float4*)in)[i];
  bf16x4 o;
  o[0] = (bf16)v.x; o[1] = (bf16)v.y; o[2] = (bf16)v.z; o[3] = (bf16)v.w;
  ((bf16x4*)out)[i] = o;
}

// ---- prep: transpose + cast: in [R,C] fp32 -> out [C,R] bf16 ----
__global__ __launch_bounds__(256) void transpose_cast(const float* __restrict__ in,
                                                      bf16* __restrict__ out, int R, int C) {
  __shared__ float tile[32][33];
  int bx = blockIdx.x * 32, by = blockIdx.y * 32;
  int tx = threadIdx.x, ty = threadIdx.y;
#pragma unroll
  for (int i = 0; i < 32; i += 8)
    tile[ty + i][tx] = in[(size_t)(by + ty + i) * C + bx + tx];
  __syncthreads();
#pragma unroll
  for (int i = 0; i < 32; i += 8)
    out[(size_t)(bx + ty + i) * R + by + tx] = (bf16)tile[tx][ty + i];
}

// ---- gemm256: 256x128 tile, BK=64, 3-stage pipeline, 4 phases/K-tile ----
// R6 re-aim: non-flash ~182 us vs ~76 us FLOP floor -> GEMMs hold the
// headroom. Old GEMMs were 2-phase vmcnt(0)-drain (the ~900 TF-family
// ceiling). This kernel ports the guide's verified T-stack:
//   T2: chunk-XOR LDS swizzle (slot = chunk ^ (row&7)), the involution
//       already proven in flash K-staging: linear gl2lds dest + pre-swizzled
//       global src + XOR'd ds_read. Kills the 16-way b128 read conflict.
//   T3: 4 phases per K-tile, each {ds_read frags; issue 1-2 staging loads;
//       s_barrier; setprio(1) 8 MFMA setprio(0)} -> cross-wave read||MFMA.
//   T4: counted vmcnt(6) once per K-tile (3-buf pipeline => boundary wait
//       retires exactly the NEXT tile's 6 loads; never drains to 0).
//   T5: setprio around MFMA clusters (pays once T3 exists).
// Geometry: 512 thr = 8 waves (4M x 2N), wave out 64x64 = acc[4][4] f32x4
// (64 AGPR). LDS 3 bufs x (A 32K + B 16K) = 144 KB dynamic. Regs ~140-190.
// Race audit: tile t+2 stages into buf((t+2)%3) = buf(t-1), fully consumed
// in iter t-1 behind two barrier generations; ph0 reads of iter t sit behind
// the vmcnt(6)+barrier that retired tile t's loads (asm memory clobber stops
// LDS-read hoisting past it).
template <bool OUT_BF16>
__global__ __launch_bounds__(512, 2) void gemm256(const bf16* __restrict__ A,
                                                  const bf16* __restrict__ Bt,
                                                  const float* __restrict__ bias,
                                                  void* __restrict__ Cptr,
                                                  int M, int N, int K) {
  extern __shared__ __align__(16) bf16 sm[];   // 3 * 24576 elems = 144 KB
  const int tid  = threadIdx.x;
  const int lane = tid & 63, w = tid >> 6;
  const int lo   = lane & 15, quad = lane >> 4;
  const int wr   = w >> 1, wc = w & 1;         // 4 M-groups x 2 N-groups
  const int xcd  = blockIdx.x & 7, g = blockIdx.x >> 3;
  const int mi_  = g & 3, n_ = g >> 2;         // 4 m-bands/XCD (A L2-resident)
  const int bm   = (xcd * 4 + mi_) * 256, bn = n_ * 128;

  const bf16* Ag = A  + (size_t)bm * K;
  const bf16* Bg = Bt + (size_t)bn * K;

  // per-lane LDS read bases (chunk = 16B = 8 bf16; 8 chunks per 64-col row)
  const int swzl  = lo & 7;
  const int laneA = (wr * 64 + lo) * 64;
  const int laneB = (wc * 64 + lo) * 64;
  const int pc0   = (quad ^ swzl) * 8;          // ks=0 chunk slot
  const int pc1   = ((4 + quad) ^ swzl) * 8;    // ks=1 chunk slot

  // staging: A 4 chunks/thread (256 rows), B 2 chunks/thread (128 rows);
  // LDS dest linear (chunk id * 16B), global source pre-XOR-swizzled.
  int aoffG[4], boffG[2];
#pragma unroll
  for (int la = 0; la < 4; ++la) {
    int ca = la * 512 + tid, row = ca >> 3, s = ca & 7;
    aoffG[la] = row * K + ((s ^ (row & 7)) * 8);
  }
#pragma unroll
  for (int lb = 0; lb < 2; ++lb) {
    int cb = lb * 512 + tid, row = cb >> 3, s = cb & 7;
    boffG[lb] = row * K + ((s ^ (row & 7)) * 8);
  }
  const int T = K >> 6;                         // 16 K-tiles

  f32x4 acc[4][4];
  const f32x4 zero = {0.f, 0.f, 0.f, 0.f};
#pragma unroll
  for (int i = 0; i < 4; ++i)
#pragma unroll
    for (int j = 0; j < 4; ++j) acc[i][j] = zero;

  // ---- prologue: tile0 -> buf0 (6 loads), tile1 -> buf1 (6 loads) ----
#pragma unroll
  for (int la = 0; la < 4; ++la)
    gl2lds16(Ag + aoffG[la], sm + (la * 512 + tid) * 8);
#pragma unroll
  for (int lb = 0; lb < 2; ++lb)
    gl2lds16(Bg + boffG[lb], sm + 16384 + (lb * 512 + tid) * 8);
#pragma unroll
  for (int la = 0; la < 4; ++la)
    gl2lds16(Ag + 64 + aoffG[la], sm + 24576 + (la * 512 + tid) * 8);
#pragma unroll
  for (int lb = 0; lb < 2; ++lb)
    gl2lds16(Bg + 64 + boffG[lb], sm + 24576 + 16384 + (lb * 512 + tid) * 8);
  asm volatile("s_waitcnt vmcnt(6)" ::: "memory");   // tile0 complete
  __builtin_amdgcn_s_barrier();

  auto body = [&](int t, bool st) __attribute__((always_inline)) {
    bf16* As_ = sm + (t % 3) * 24576;
    bf16* Bs_ = As_ + 16384;
    bf16* An_ = sm + ((t + 2) % 3) * 24576;
    bf16* Bn_ = An_ + 16384;
    const size_t kg = (size_t)(t + 2) * 64;
    bf16x8 av0, av1, bv[4];

    // ---- ph0: ks0, mi 0-1; stage A chunks 0,1 of tile t+2 ----
    av0 = *(const bf16x8*)&As_[laneA + 0 * 1024 + pc0];
    av1 = *(const bf16x8*)&As_[laneA + 1 * 1024 + pc0];
#pragma unroll
    for (int j = 0; j < 4; ++j)
      bv[j] = *(const bf16x8*)&Bs_[laneB + j * 1024 + pc0];
    if (st) {
      gl2lds16(Ag + kg + aoffG[0], An_ + (0 * 512 + tid) * 8);
      gl2lds16(Ag + kg + aoffG[1], An_ + (1 * 512 + tid) * 8);
    }
    __builtin_amdgcn_s_barrier();
    __builtin_amdgcn_s_setprio(1);
#pragma unroll
    for (int j = 0; j < 4; ++j) {
      acc[0][j] = MFMA16(av0, bv[j], acc[0][j]);
      acc[1][j] = MFMA16(av1, bv[j], acc[1][j]);
    }
    __builtin_amdgcn_s_setprio(0);

    // ---- ph1: ks0, mi 2-3; stage A chunks 2,3 ----
    av0 = *(const bf16x8*)&As_[laneA + 2 * 1024 + pc0];
    av1 = *(const bf16x8*)&As_[laneA + 3 * 1024 + pc0];
    if (st) {
      gl2lds16(Ag + kg + aoffG[2], An_ + (2 * 512 + tid) * 8);
      gl2lds16(Ag + kg + aoffG[3], An_ + (3 * 512 + tid) * 8);
    }
    __builtin_amdgcn_s_barrier();
    __builtin_amdgcn_s_setprio(1);
#pragma unroll
    for (int j = 0; j < 4; ++j) {
      acc[2][j] = MFMA16(av0, bv[j], acc[2][j]);
      acc[3][j] = MFMA16(av1, bv[j], acc[3][j]);
    }
    __builtin_amdgcn_s_setprio(0);

    // ---- ph2: ks1, mi 0-1; stage B chunk 0 ----
    av0 = *(const bf16x8*)&As_[laneA + 0 * 1024 + pc1];
    av1 = *(const bf16x8*)&As_[laneA + 1 * 1024 + pc1];
#pragma unroll
    for (int j = 0; j < 4; ++j)
      bv[j] = *(const bf16x8*)&Bs_[laneB + j * 1024 + pc1];
    if (st)
      gl2lds16(Bg + kg + boffG[0], Bn_ + (0 * 512 + tid) * 8);
    __builtin_amdgcn_s_barrier();
    __builtin_amdgcn_s_setprio(1);
#pragma unroll
    for (int j = 0; j < 4; ++j) {
      acc[0][j] = MFMA16(av0, bv[j], acc[0][j]);
      acc[1][j] = MFMA16(av1, bv[j], acc[1][j]);
    }
    __builtin_amdgcn_s_setprio(0);

    // ---- ph3: ks1, mi 2-3; stage B chunk 1 ----
    av0 = *(const bf16x8*)&As_[laneA + 2 * 1024 + pc1];
    av1 = *(const bf16x8*)&As_[laneA + 3 * 1024 + pc1];
    if (st)
      gl2lds16(Bg + kg + boffG[1], Bn_ + (1 * 512 + tid) * 8);
    __builtin_amdgcn_s_barrier();
    __builtin_amdgcn_s_setprio(1);
#pragma unroll
    for (int j = 0; j < 4; ++j) {
      acc[2][j] = MFMA16(av0, bv[j], acc[2][j]);
      acc[3][j] = MFMA16(av1, bv[j], acc[3][j]);
    }
    __builtin_amdgcn_s_setprio(0);
  };

  // main loop: counted vmcnt(6) boundary — retires exactly tile t+1's loads
#pragma unroll 1
  for (int t = 0; t < T - 2; ++t) {
    body(t, true);
    asm volatile("s_waitcnt vmcnt(6)" ::: "memory");
    __builtin_amdgcn_s_barrier();
  }
  body(T - 2, false);
  asm volatile("s_waitcnt vmcnt(0)" ::: "memory");
  __builtin_amdgcn_s_barrier();
  body(T - 1, false);

  // ---- epilogue: bias + store (register-only, no barrier needed) ----
#pragma unroll
  for (int j = 0; j < 4; ++j) {
    int cg = bn + wc * 64 + j * 16 + lo;
    float bsv = bias[cg];
#pragma unroll
    for (int i = 0; i < 4; ++i) {
      int rg = bm + wr * 64 + i * 16 + quad * 4;
#pragma unroll
      for (int r = 0; r < 4; ++r) {
        float v = acc[i][j][r] + bsv;
        if (OUT_BF16) ((bf16*)Cptr)[(size_t)(rg + r) * N + cg] = (bf16)v;
        else          ((float*)Cptr)[(size_t)(rg + r) * N + cg] = v;
      }
    }
  }
}

// ---- flash attention v11 (verified 101.6 us @ R3; occupancy levers closed) ----
__global__ __launch_bounds__(256, 2) void flash_attn(const bf16* __restrict__ qkv,
                                                     bf16* __restrict__ out) {
  __shared__ __align__(16) bf16 smem[16384];
  bf16* const Ksm = smem;          // [2][64*64], chunk-swizzled rows
  bf16* const Vsm = smem + 8192;   // [2][64*64], [d][s] chunk-swizzled

  const int tid  = threadIdx.x;
  const int lane = tid & 63, wq = tid >> 6;
  const int l31  = lane & 31;
  const int e    = lane >> 5;           // hi1
  const int hi8  = e * 8, hi4 = e * 4;

  const int bid = blockIdx.x;
  const int qb  = bid >> 6;             // 0..7 (256 q each)
  const int bh  = bid & 63;
  const int h   = bh & 15;
  const int b   = bh >> 4;
  const int q0  = qb * 256;
  const size_t rowb = (size_t)b * S_;
  const bf16* qbase = qkv + rowb * NQKV + h * HD_;
  const bf16* kbase = qbase + D_;
  const bf16* vbase = qbase + 2 * D_;

  bf16x8 qfA[4], qfB[4];
  {
    const bf16* qrow0 = qbase + (size_t)(q0 + wq * 64 + l31) * NQKV;
    const bf16* qrow1 = qrow0 + (size_t)32 * NQKV;
#pragma unroll
    for (int c = 0; c < 4; ++c) {
      qfA[c] = *(const bf16x8*)(qrow0 + c * 16 + hi8);
      qfB[c] = *(const bf16x8*)(qrow1 + c * 16 + hi8);
    }
  }

  int kq_off[2];
#pragma unroll
  for (int it = 0; it < 2; ++it) {
    int ci = it * 256 + tid;
    int s  = ci >> 3;
    int x  = (ci & 7) ^ (s & 7);
    kq_off[it] = s * NQKV + x * 8;
  }
  int vs_d[2], vs_s[2], vs_off[2];
#pragma unroll
  for (int u = 0; u < 2; ++u) {
    int idx = u * 256 + tid;
    int d0 = (idx & 31) * 2;
    int s0 = (idx >> 5) * 4;
    vs_d[u] = d0;
    vs_s[u] = s0;
    vs_off[u] = (((s0 >> 3) ^ ((d0 >> 1) & 7)) * 8) + (s0 & 7);
  }

  uint32_t vreg[2][4];

#pragma unroll
  for (int it = 0; it < 2; ++it)
    gl2lds16(kbase + kq_off[it], Ksm + (it * 256 + wq * 64) * 8);
#pragma unroll
  for (int u = 0; u < 2; ++u)
#pragma unroll
    for (int j = 0; j < 4; ++j)
      vreg[u][j] = *(const uint32_t*)(vbase + (size_t)(vs_s[u] + j) * NQKV + vs_d[u]);

  const f32x16 zero16 = {0.f,0.f,0.f,0.f,0.f,0.f,0.f,0.f,0.f,0.f,0.f,0.f,0.f,0.f,0.f,0.f};
  f32x16 oacc[2][2];
  oacc[0][0] = zero16; oacc[0][1] = zero16;
  oacc[1][0] = zero16; oacc[1][1] = zero16;
  f32x2 psA = {0.f, 0.f}, psB = {0.f, 0.f};
  const float c2 = 0.125f * 1.44269504088896341f;   // scale * log2(e)

  for (int kt = 0; kt < 32; ++kt) {
    const int buf = kt & 1;
#pragma unroll
    for (int u = 0; u < 2; ++u) {
      int d0 = vs_d[u];
      uint32_t lo0 = __builtin_amdgcn_perm(vreg[u][1], vreg[u][0], 0x05040100u);
      uint32_t lo1 = __builtin_amdgcn_perm(vreg[u][3], vreg[u][2], 0x05040100u);
      uint32_t hi0 = __builtin_amdgcn_perm(vreg[u][1], vreg[u][0], 0x07060302u);
      uint32_t hi1 = __builtin_amdgcn_perm(vreg[u][3], vreg[u][2], 0x07060302u);
      u32x2 lov = {lo0, lo1}, hiv = {hi0, hi1};
      *(u32x2*)&Vsm[buf * 4096 + (d0 + 0) * 64 + vs_off[u]] = lov;
      *(u32x2*)&Vsm[buf * 4096 + (d0 + 1) * 64 + vs_off[u]] = hiv;
    }
    __syncthreads();

    {
      int ktn = (kt + 1 < 32) ? kt + 1 : 31;
      const bf16* kb = kbase + (size_t)ktn * 64 * NQKV;
#pragma unroll
      for (int it = 0; it < 2; ++it)
        gl2lds16(kb + kq_off[it], Ksm + (buf ^ 1) * 4096 + (it * 256 + wq * 64) * 8);
    }
    {
      int ktn = (kt + 1 < 32) ? kt + 1 : 31;
      const bf16* vb = vbase + (size_t)ktn * 64 * NQKV;
#pragma unroll
      for (int u = 0; u < 2; ++u)
#pragma unroll
        for (int j = 0; j < 4; ++j)
          vreg[u][j] = *(const uint32_t*)(vb + (size_t)(vs_s[u] + j) * NQKV + vs_d[u]);
    }

#pragma unroll
    for (int kk = 0; kk < 2; ++kk) {
      f32x16 sA = zero16, sB = zero16;
      int srow = kk * 32 + l31;
      int swz  = (srow & 7) * 8;
      __builtin_amdgcn_s_setprio(1);
#pragma unroll
      for (int c = 0; c < 4; ++c) {
        bf16x8 kf = *(const bf16x8*)&Ksm[buf * 4096 + srow * 64 + ((c * 16 + hi8) ^ swz)];
        sA = __builtin_amdgcn_mfma_f32_32x32x16_bf16(kf, qfA[c], sA, 0, 0, 0);
        sB = __builtin_amdgcn_mfma_f32_32x32x16_bf16(kf, qfB[c], sB, 0, 0, 0);
      }
      __builtin_amdgcn_s_setprio(0);

      uint32_t Q8a[8], Q8b[8];
#pragma unroll
      for (int i = 0; i < 8; ++i) {
        f32x2 sva, svb;
        sva[0] = sA[2 * i]; sva[1] = sA[2 * i + 1];
        svb[0] = sB[2 * i]; svb[1] = sB[2 * i + 1];
        f32x2 ta = sva * c2 - 16.0f;
        f32x2 tb = svb * c2 - 16.0f;
        float a0 = __builtin_amdgcn_exp2f(ta[0]);
        float a1 = __builtin_amdgcn_exp2f(ta[1]);
        float b0 = __builtin_amdgcn_exp2f(tb[0]);
        float b1 = __builtin_amdgcn_exp2f(tb[1]);
        psA += (f32x2){a0, a1};
        psB += (f32x2){b0, b1};
        Q8a[i] = pkbf16(a0, a1);
        Q8b[i] = pkbf16(b0, b1);
      }

#pragma unroll
      for (int mh = 0; mh < 2; ++mh) {
        const int m = kk * 2 + mh, bq = mh * 4;
        u32x4 pda, pdb;
#if __has_builtin(__builtin_amdgcn_permlane32_swap)
        u32x2 wa0 = __builtin_amdgcn_permlane32_swap(Q8a[bq],     Q8a[bq + 2], false, false);
        u32x2 wa1 = __builtin_amdgcn_permlane32_swap(Q8a[bq + 1], Q8a[bq + 3], false, false);
        pda[0] = wa0[0]; pda[1] = wa1[0]; pda[2] = wa0[1]; pda[3] = wa1[1];
        u32x2 wb0 = __builtin_amdgcn_permlane32_swap(Q8b[bq],     Q8b[bq + 2], false, false);
        u32x2 wb1 = __builtin_amdgcn_permlane32_swap(Q8b[bq + 1], Q8b[bq + 3], false, false);
        pdb[0] = wb0[0]; pdb[1] = wb1[0]; pdb[2] = wb0[1]; pdb[3] = wb1[1];
#else
        {
          uint32_t s0 = e ? Q8a[bq]     : Q8a[bq + 2];
          uint32_t s1 = e ? Q8a[bq + 1] : Q8a[bq + 3];
          uint32_t r0 = __shfl_xor(s0, 32);
          uint32_t r1 = __shfl_xor(s1, 32);
          pda[0] = e ? r0 : Q8a[bq];
          pda[1] = e ? r1 : Q8a[bq + 1];
          pda[2] = e ? Q8a[bq + 2] : r0;
          pda[3] = e ? Q8a[bq + 3] : r1;
        }
        {
          uint32_t s0 = e ? Q8b[bq]     : Q8b[bq + 2];
          uint32_t s1 = e ? Q8b[bq + 1] : Q8b[bq + 3];
          uint32_t r0 = __shfl_xor(s0, 32);
          uint32_t r1 = __shfl_xor(s1, 32);
          pdb[0] = e ? r0 : Q8b[bq];
          pdb[1] = e ? r1 : Q8b[bq + 1];
          pdb[2] = e ? Q8b[bq + 2] : r0;
          pdb[3] = e ? Q8b[bq + 3] : r1;
        }
#endif
        bf16x8 pfa = __builtin_bit_cast(bf16x8, pda);
        bf16x8 pfb = __builtin_bit_cast(bf16x8, pdb);
        __builtin_amdgcn_s_setprio(1);
#pragma unroll
        for (int dt = 0; dt < 2; ++dt) {
          int drow = dt * 32 + l31;
          int swv  = (drow >> 1) & 7;
          bf16x8 vf = *(const bf16x8*)&Vsm[buf * 4096 + drow * 64 + (((m * 2 + e) ^ swv) * 8)];
          oacc[dt][0] = __builtin_amdgcn_mfma_f32_32x32x16_bf16(vf, pfa, oacc[dt][0], 0, 0, 0);
          oacc[dt][1] = __builtin_amdgcn_mfma_f32_32x32x16_bf16(vf, pfb, oacc[dt][1], 0, 0, 0);
        }
        __builtin_amdgcn_s_setprio(0);
      }
    }
  }

  float lsumA = psA[0] + psA[1];
  float lsumB = psB[0] + psB[1];
  lsumA += __shfl_xor(lsumA, 32);
  lsumB += __shfl_xor(lsumB, 32);

  __syncthreads();
  bf16* Os = smem;                       // [256][64] bf16, chunk-XOR ((row>>1)&7)
  {
    float invA = 1.f / lsumA;
    float invB = 1.f / lsumB;
#pragma unroll
    for (int qs = 0; qs < 2; ++qs) {
      float inv = qs ? invB : invA;
      int ql = wq * 64 + qs * 32 + l31;
      int swO = (ql >> 1) & 7;
#pragma unroll
      for (int dt = 0; dt < 2; ++dt) {
#pragma unroll
        for (int g = 0; g < 4; ++g) {
          bf16x4 ov;
#pragma unroll
          for (int jj = 0; jj < 4; ++jj)
            ov[jj] = (bf16)(oacc[dt][qs][g * 4 + jj] * inv);
          *(bf16x4*)&Os[ql * 64 + (((dt * 4 + g) ^ swO) * 8) + hi4] = ov;
        }
      }
    }
  }
  __syncthreads();
#pragma unroll
  for (int it = 0; it < 8; ++it) {
    int idx = it * 256 + tid;
    int row = idx >> 3, c8 = idx & 7;
    bf16x8 t = *(const bf16x8*)&Os[row * 64 + ((c8 ^ ((row >> 1) & 7)) * 8)];
    *(bf16x8*)&out[(rowb + q0 + row) * D_ + h * HD_ + c8 * 8] = t;
  }
}

extern "C" void kernel_launch(void* const* d_in, const int* in_sizes, int n_in,
                              void* d_out, int out_size, void* d_ws, size_t ws_size,
                              hipStream_t stream) {
  const float* x     = (const float*)d_in[0];
  const float* w_qkv = (const float*)d_in[1];
  const float* b_qkv = (const float*)d_in[2];
  const float* w_out = (const float*)d_in[3];
  const float* b_out = (const float*)d_in[4];
  float* out = (float*)d_out;

  char* ws = (char*)d_ws;
  bf16* xb    = (bf16*)(ws);                         // 16 MB
  bf16* wqkvT = (bf16*)(ws + (size_t)16777216);      //  6 MB
  bf16* woutT = (bf16*)(ws + (size_t)23068672);      //  2 MB
  bf16* qkvb  = (bf16*)(ws + (size_t)25165824);      // 48 MB
  bf16* attnb = (bf16*)(ws + (size_t)75497472);      // 16 MB

  // allow 144 KB dynamic LDS for gemm256 (host-side attr; set once)
  static int attr_done = 0;
  if (!attr_done) {
    hipFuncSetAttribute(reinterpret_cast<const void*>(&gemm256<true>),
                        hipFuncAttributeMaxDynamicSharedMemorySize, 147456);
    hipFuncSetAttribute(reinterpret_cast<const void*>(&gemm256<false>),
                        hipFuncAttributeMaxDynamicSharedMemorySize, 147456);
    attr_done = 1;
  }

  cast_f32_bf16<<<(M_ * D_ / 4 + 255) / 256, 256, 0, stream>>>(x, xb, M_ * D_ / 4);
  transpose_cast<<<dim3(NQKV / 32, D_ / 32), dim3(32, 8), 0, stream>>>(w_qkv, wqkvT, D_, NQKV);
  transpose_cast<<<dim3(D_ / 32, D_ / 32), dim3(32, 8), 0, stream>>>(w_out, woutT, D_, D_);

  // qkv GEMM: M=8192, N=3072 -> 32 m-bands x 24 n-cols = 768 blocks (3 rounds)
  gemm256<true><<<(M_ / 256) * (NQKV / 128), 512, 147456, stream>>>(
      xb, wqkvT, b_qkv, (void*)qkvb, M_, NQKV, D_);

  flash_attn<<<B_ * H_ * (S_ / 256), 256, 0, stream>>>(qkvb, attnb);

  // out-proj GEMM: M=8192, N=1024 -> 32 x 8 = 256 blocks (1 round)
  gemm256<false><<<(M_ / 256) * (D_ / 128), 512, 147456, stream>>>(
      attnb, woutT, b_out, (void*)out, M_, D_, D_);
}